// Round 17
// baseline (265.632 us; speedup 1.0000x reference)
//
#include <hip/hip_runtime.h>
#include <hip/hip_bf16.h>

#define N_NODES 50000
#define N_EDGES 250000
#define NHEAD   12
#define NH      (N_NODES * NHEAD)   /* 600000 rows of 64 */
#define ROW_TILES (NH / 16)         /* 37500 */
#define NGEMMB  2344                 /* gemm blocks: 9376 waves x 4 tiles */
#define NFILLB  977                  /* fill blocks */

typedef __bf16 bf16_t;
typedef __bf16 bf16x8 __attribute__((ext_vector_type(8)));
typedef __bf16 bf16x4 __attribute__((ext_vector_type(4)));
typedef float  f32x4  __attribute__((ext_vector_type(4)));

__device__ __forceinline__ bf16x8 cvt8(f32x4 a, f32x4 b) {
    bf16x8 r;
    r[0] = (bf16_t)a[0]; r[1] = (bf16_t)a[1]; r[2] = (bf16_t)a[2]; r[3] = (bf16_t)a[3];
    r[4] = (bf16_t)b[0]; r[5] = (bf16_t)b[1]; r[6] = (bf16_t)b[2]; r[7] = (bf16_t)b[3];
    return r;
}

__device__ __forceinline__ uint2 pack4(f32x4 z) {
    bf16x4 p;
    p[0] = (bf16_t)z[0]; p[1] = (bf16_t)z[1]; p[2] = (bf16_t)z[2]; p[3] = (bf16_t)z[3];
    union { bf16x4 b; uint2 u; } c; c.b = p;
    return c.u;
}

// 4-lane-group in-register transpose. In: c0..c3 = F[r0+lr][16nt+4lg..+3].
// Out: g0..g3 = 4-col sub-chunks of F[r0+lr][16lg..16lg+15].
__device__ __forceinline__ void xpose4(uint2 c0, uint2 c1, uint2 c2, uint2 c3,
                                       int lr, int lg,
                                       uint2& g0, uint2& g1, uint2& g2, uint2& g3) {
    g0 = g1 = g2 = g3 = make_uint2(0, 0);
#pragma unroll
    for (int k = 0; k < 4; ++k) {
        int sel = (lg - k) & 3;
        uint2 P = (sel == 0) ? c0 : (sel == 1) ? c1 : (sel == 2) ? c2 : c3;
        int srcl = lr + 16 * ((lg + k) & 3);
        uint2 R;
        R.x = (unsigned)__shfl((int)P.x, srcl, 64);
        R.y = (unsigned)__shfl((int)P.y, srcl, 64);
        int m = (lg + k) & 3;
        g0 = (m == 0) ? R : g0;
        g1 = (m == 1) ? R : g1;
        g2 = (m == 2) ? R : g2;
        g3 = (m == 3) ? R : g3;
    }
}

// ---------------- prep: degree histogram (int4 edge reads), weight cvt, ul/ur ----------------
__global__ __launch_bounds__(256) void k_deg_prep(
    const int* __restrict__ dst, int* __restrict__ deg,
    const float* __restrict__ wfc, const float* __restrict__ wres,
    const float* __restrict__ attl, const float* __restrict__ attr,
    bf16_t* __restrict__ wfb, bf16_t* __restrict__ wrb,
    bf16_t* __restrict__ ulb, bf16_t* __restrict__ urb)
{
    int b = blockIdx.x;
    if (b < 245) {
        int i4 = b * 256 + threadIdx.x;          // 62500 int4s = 250000 edges exactly
        if (i4 < N_EDGES / 4) {
            int4 q = reinterpret_cast<const int4*>(dst)[i4];
            atomicAdd(&deg[q.x], 1);
            atomicAdd(&deg[q.y], 1);
            atomicAdd(&deg[q.z], 1);
            atomicAdd(&deg[q.w], 1);
        }
    } else if (b < 261) {
        int t = (b - 245) * 256 + threadIdx.x;   // 0..4095
        wfb[t] = (bf16_t)wfc[t];
        wrb[t] = (bf16_t)wres[t];
    } else if (b < 265) {
        int u = (b - 261) * 256 + threadIdx.x;   // 0..1023
        int hh = u >> 6, d = u & 63;
        float s = 0.f;
        if (hh < NHEAD) {
#pragma unroll 8
            for (int e = 0; e < 64; ++e) s += attl[hh * 64 + e] * wfc[e * 64 + d];
        }
        ulb[u] = (bf16_t)s;
    } else {
        int u = (b - 265) * 256 + threadIdx.x;   // 0..1023
        int hh = u >> 6, d = u & 63;
        float s = 0.f;
        if (hh < NHEAD) {
#pragma unroll 8
            for (int e = 0; e < 64; ++e) s += attr[hh * 64 + e] * wfc[e * 64 + d];
        }
        urb[u] = (bf16_t)s;
    }
}

// single block, 1024 threads, 52 nodes/thread. Writes ONLY cursor (=segment
// starts); fill atomics exhaust cursor into segment ENDs; k_agg reads
// beg=cursor[d-1], end=cursor[d].
__global__ __launch_bounds__(1024) void k_scan(const int* __restrict__ deg,
                                               int* __restrict__ cursor) {
    __shared__ int s[1024];
    const int CH = 52;
    int t = threadIdx.x;
    int base = t * CH;
    int loc[CH];
    if (base + CH <= N_NODES) {
        const int4* p = reinterpret_cast<const int4*>(deg + base);
#pragma unroll
        for (int i = 0; i < CH / 4; ++i) {
            int4 q = p[i];
            loc[4 * i + 0] = q.x; loc[4 * i + 1] = q.y;
            loc[4 * i + 2] = q.z; loc[4 * i + 3] = q.w;
        }
    } else {
#pragma unroll
        for (int i = 0; i < CH; ++i) {
            int idx = base + i;
            loc[i] = (idx < N_NODES) ? deg[idx] : 0;
        }
    }
    int sum = 0;
#pragma unroll
    for (int i = 0; i < CH; ++i) sum += loc[i];
    s[t] = sum;
    __syncthreads();
    for (int off = 1; off < 1024; off <<= 1) {
        int v = (t >= off) ? s[t - off] : 0;
        __syncthreads();
        s[t] += v;
        __syncthreads();
    }
    int run = s[t] - sum;
#pragma unroll
    for (int i = 0; i < CH; ++i) {
        int idx = base + i;
        if (idx < N_NODES) {
            cursor[idx] = run;
            run += loc[i];
        }
    }
}

// ---------------- fused persistent GEMM + CSR-fill (static ping-pong) ----------------
// Blocks 0..2343: gemm, 4 tiles/wave as a FULLY UNROLLED ping-pong over two
// named register buffers — no dynamic loop, no phi moves of load data, so no
// per-tile vmcnt(0) drain (R14/R16's rotation forced full load+store retire
// each tile). Blocks 2344+: CSR fill. Epilogue: in-register shuffle transpose.
#define LOAD_A(B0, B1, B2, B3, T) {                                   \
    int ab_ = ((T) * 16 + lr) * 16 + lg * 2;                          \
    B0 = __builtin_nontemporal_load(hv + ab_);                        \
    B1 = __builtin_nontemporal_load(hv + ab_ + 1);                    \
    B2 = __builtin_nontemporal_load(hv + ab_ + 8);                    \
    B3 = __builtin_nontemporal_load(hv + ab_ + 9); }

#define COMP_T(B0, B1, B2, B3, TILE) {                                              \
    bf16x8 a0_ = cvt8(B0, B1), a1_ = cvt8(B2, B3);                                  \
    int r0_ = (TILE) << 4;                                                          \
    int r_  = r0_ + lr;                                                             \
    int hh_ = r_ % NHEAD;                                                           \
    f32x4 dl_ = {0.f,0.f,0.f,0.f}, dr_ = {0.f,0.f,0.f,0.f};                         \
    dl_ = __builtin_amdgcn_mfma_f32_16x16x32_bf16(ul0, a0_, dl_, 0, 0, 0);          \
    dl_ = __builtin_amdgcn_mfma_f32_16x16x32_bf16(ul1, a1_, dl_, 0, 0, 0);          \
    dr_ = __builtin_amdgcn_mfma_f32_16x16x32_bf16(ur0, a0_, dr_, 0, 0, 0);          \
    dr_ = __builtin_amdgcn_mfma_f32_16x16x32_bf16(ur1, a1_, dr_, 0, 0, 0);          \
    if (lg == (hh_ >> 2)) {                                                         \
        _Pragma("unroll")                                                           \
        for (int j = 0; j < 4; ++j)                                                 \
            if ((hh_ & 3) == j) { al[r_] = dl_[j]; ar[r_] = dr_[j]; }               \
    }                                                                               \
    uint2 pf_[4], pe_[4];                                                           \
    _Pragma("unroll")                                                               \
    for (int nt = 0; nt < 4; ++nt) {                                                \
        int brow_ = (nt * 16 + lr) * 8;                                             \
        f32x4 z_ = {0.f,0.f,0.f,0.f};                                               \
        z_ = __builtin_amdgcn_mfma_f32_16x16x32_bf16(wf[brow_ + lg],     a0_, z_, 0, 0, 0); \
        z_ = __builtin_amdgcn_mfma_f32_16x16x32_bf16(wf[brow_ + 4 + lg], a1_, z_, 0, 0, 0); \
        f32x4 y_ = {0.f,0.f,0.f,0.f};                                               \
        y_ = __builtin_amdgcn_mfma_f32_16x16x32_bf16(wr[brow_ + lg],     a0_, y_, 0, 0, 0); \
        y_ = __builtin_amdgcn_mfma_f32_16x16x32_bf16(wr[brow_ + 4 + lg], a1_, y_, 0, 0, 0); \
        pf_[nt] = pack4(z_);                                                        \
        pe_[nt] = pack4(y_);                                                        \
    }                                                                               \
    uint2 f0_, f1_, f2_, f3_, e0_, e1_, e2_, e3_;                                   \
    xpose4(pf_[0], pf_[1], pf_[2], pf_[3], lr, lg, f0_, f1_, f2_, f3_);             \
    xpose4(pe_[0], pe_[1], pe_[2], pe_[3], lr, lg, e0_, e1_, e2_, e3_);             \
    uint4 flo_ = make_uint4(f0_.x, f0_.y, f1_.x, f1_.y);                            \
    uint4 fhi_ = make_uint4(f2_.x, f2_.y, f3_.x, f3_.y);                            \
    uint4 elo_ = make_uint4(e0_.x, e0_.y, e1_.x, e1_.y);                            \
    uint4 ehi_ = make_uint4(e2_.x, e2_.y, e3_.x, e3_.y);                            \
    *reinterpret_cast<uint4*>(ft   + r_ * 64 + lg * 16)     = flo_;                 \
    *reinterpret_cast<uint4*>(ft   + r_ * 64 + lg * 16 + 8) = fhi_;                 \
    *reinterpret_cast<uint4*>(resb + r_ * 64 + lg * 16)     = elo_;                 \
    *reinterpret_cast<uint4*>(resb + r_ * 64 + lg * 16 + 8) = ehi_; }

__global__ __launch_bounds__(256) void k_fill_gemm(
    const int* __restrict__ src, const int* __restrict__ dst,
    int* __restrict__ cursor, int* __restrict__ csr_src,
    const float* __restrict__ h,
    const bf16_t* __restrict__ wfb,
    const bf16_t* __restrict__ wrb,
    const bf16_t* __restrict__ ulb,
    const bf16_t* __restrict__ urb,
    bf16_t* __restrict__ ft,
    bf16_t* __restrict__ resb,
    float* __restrict__ al,
    float* __restrict__ ar)
{
    int bid = blockIdx.x;
    if (bid >= NGEMMB) {                         // fill role
        int i = (bid - NGEMMB) * 256 + threadIdx.x;
        if (i < N_EDGES) {
            int d = dst[i];
            int pos = atomicAdd(&cursor[d], 1);
            csr_src[pos] = src[i];
        }
        return;
    }
    int wv   = threadIdx.x >> 6;
    int lane = threadIdx.x & 63;
    int lr = lane & 15, lg = lane >> 4;

    const f32x4*  hv  = reinterpret_cast<const f32x4*>(h);
    const bf16x8* wf  = reinterpret_cast<const bf16x8*>(wfb);
    const bf16x8* wr  = reinterpret_cast<const bf16x8*>(wrb);
    const bf16x8* ulv = reinterpret_cast<const bf16x8*>(ulb);
    const bf16x8* urv = reinterpret_cast<const bf16x8*>(urb);
    bf16x8 ul0 = ulv[lr * 8 + lg], ul1 = ulv[lr * 8 + 4 + lg];
    bf16x8 ur0 = urv[lr * 8 + lg], ur1 = urv[lr * 8 + 4 + lg];

    const int nw = NGEMMB * 4;                   // 9376 gemm waves
    int t0 = bid * 4 + wv;
    int t1 = t0 + nw, t2 = t0 + 2 * nw, t3 = t0 + 3 * nw;
    bool v0 = t0 < ROW_TILES, v1 = t1 < ROW_TILES,
         v2 = t2 < ROW_TILES, v3 = t3 < ROW_TILES;

    f32x4 A0, A1, A2, A3;     // ping buffer
    f32x4 B0, B1, B2, B3;     // pong buffer

    if (v0) LOAD_A(A0, A1, A2, A3, t0);
    if (v1) LOAD_A(B0, B1, B2, B3, t1);
    if (v0) COMP_T(A0, A1, A2, A3, t0);
    if (v2) LOAD_A(A0, A1, A2, A3, t2);
    if (v1) COMP_T(B0, B1, B2, B3, t1);
    if (v3) LOAD_A(B0, B1, B2, B3, t3);
    if (v2) COMP_T(A0, A1, A2, A3, t2);
    if (v3) COMP_T(B0, B1, B2, B3, t3);
}

// ---------------- fused edge-softmax + aggregate + residual + relu ----------------
// ONE WAVE PER DST NODE, all 12 heads; DB=8 edges in flight (16 fat ft loads).
// Segments: beg = cur[d0-1] (post-fill), end = cur[d0]. Cooperative weights:
// lane l<48 computes (edge l/12 and l/12+4, head l%12) -> 2 gather instrs per
// 8-edge batch; shfl distributes.
#define DB 8
__global__ __launch_bounds__(256) void k_agg(
    const int* __restrict__ cur, const int* __restrict__ csr_src,
    const float* __restrict__ al, const float* __restrict__ ar,
    const bf16_t* __restrict__ ft, const bf16_t* __restrict__ resb,
    float* __restrict__ out)
{
    int d0 = (blockIdx.x * 256 + threadIdx.x) >> 6;
    d0 = __builtin_amdgcn_readfirstlane(d0);
    if (d0 >= N_NODES) return;
    int l  = threadIdx.x & 63;
    int hA = l >> 3;              // part A: head l>>3, feats (l&7)*8..+7
    int hB = 8 + (l >> 4);        // part B: head 8+(l>>4), feats (l&15)*4..+3
    int u_l = l / 12;             // weight lanes: l<48 -> edge pair (u_l, u_l+4)
    int h_l = l - u_l * 12;
    int beg = d0 ? cur[d0 - 1] : 0;                       // s_load
    int end = cur[d0];
    float arW = 0.f;
    if (l < 48) arW = ar[d0 * NHEAD + h_l];

    float accA[8] = {0,0,0,0,0,0,0,0};
    float accB[4] = {0,0,0,0};
    float denA = 0.f, denB = 0.f;

    for (int j0 = beg; j0 < end; j0 += DB) {
        int idx[DB];
#pragma unroll
        for (int u = 0; u < DB; ++u) {
            int j = j0 + u;
            idx[u] = csr_src[(j < end) ? j : beg];        // scalar (uniform addr)
        }
        // cooperative weights: lanes 0..47, two edges each
        float wv0 = 0.f, wv1 = 0.f;
        {
            int e0 = idx[0], e1 = idx[4];
            e0 = (u_l == 1) ? idx[1] : e0;  e1 = (u_l == 1) ? idx[5] : e1;
            e0 = (u_l == 2) ? idx[2] : e0;  e1 = (u_l == 2) ? idx[6] : e1;
            e0 = (u_l == 3) ? idx[3] : e0;  e1 = (u_l == 3) ? idx[7] : e1;
            if (l < 48) {
                float x0 = al[e0 * NHEAD + h_l] + arW;
                float x1 = al[e1 * NHEAD + h_l] + arW;
                x0 = (x0 > 0.f) ? x0 : 0.2f * x0;         // leaky_relu
                x1 = (x1 > 0.f) ? x1 : 0.2f * x1;
                wv0 = ((j0 + u_l)     < end) ? __expf(x0) : 0.f;
                wv1 = ((j0 + 4 + u_l) < end) ? __expf(x1) : 0.f;
            }
        }
        float wA[DB], wB[DB];
#pragma unroll
        for (int u = 0; u < 4; ++u) {
            wA[u]     = __shfl(wv0, u * 12 + hA, 64);
            wB[u]     = __shfl(wv0, u * 12 + hB, 64);
            wA[u + 4] = __shfl(wv1, u * 12 + hA, 64);
            wB[u + 4] = __shfl(wv1, u * 12 + hB, 64);
        }
        bf16x8 vA[DB]; bf16x4 vB[DB];
#pragma unroll
        for (int u = 0; u < DB; ++u) {
            const bf16_t* row = ft + idx[u] * 768;
            vA[u] = *reinterpret_cast<const bf16x8*>(row + 8 * l);
            vB[u] = *reinterpret_cast<const bf16x4*>(row + 512 + 4 * l);
        }
#pragma unroll
        for (int u = 0; u < DB; ++u) {
            denA += wA[u]; denB += wB[u];
#pragma unroll
            for (int k = 0; k < 8; ++k) accA[k] += wA[u] * (float)vA[u][k];
#pragma unroll
            for (int k = 0; k < 4; ++k) accB[k] += wB[u] * (float)vB[u][k];
        }
    }

    const bf16_t* rrow = resb + d0 * 768;
    bf16x8 rA = __builtin_nontemporal_load(reinterpret_cast<const bf16x8*>(rrow + 8 * l));
    bf16x4 rB = __builtin_nontemporal_load(reinterpret_cast<const bf16x4*>(rrow + 512 + 4 * l));
    float* orow = out + d0 * 768;
    f32x4 o0, o1, o2;
    float ia = 1.f / denA, ib = 1.f / denB;
#pragma unroll
    for (int k = 0; k < 4; ++k) {
        float x = (float)rA[k] + accA[k] * ia;         o0[k] = x > 0.f ? x : 0.f;
        float y = (float)rA[k + 4] + accA[k + 4] * ia; o1[k] = y > 0.f ? y : 0.f;
        float z = (float)rB[k] + accB[k] * ib;         o2[k] = z > 0.f ? z : 0.f;
    }
    __builtin_nontemporal_store(o0, reinterpret_cast<f32x4*>(orow + 8 * l));
    __builtin_nontemporal_store(o1, reinterpret_cast<f32x4*>(orow + 8 * l + 4));
    __builtin_nontemporal_store(o2, reinterpret_cast<f32x4*>(orow + 512 + 4 * l));
}

extern "C" void kernel_launch(void* const* d_in, const int* in_sizes, int n_in,
                              void* d_out, int out_size, void* d_ws, size_t ws_size,
                              hipStream_t stream) {
    const float* h    = (const float*)d_in[0];
    const float* wfc  = (const float*)d_in[1];
    const float* attl = (const float*)d_in[2];
    const float* attr = (const float*)d_in[3];
    const float* wres = (const float*)d_in[4];
    const int*   src  = (const int*)d_in[5];
    const int*   dst  = (const int*)d_in[6];
    float* out = (float*)d_out;

    char* ws = (char*)d_ws;
    bf16_t* ft     = (bf16_t*)(ws + 0);          //  76,800,000 B
    bf16_t* resb   = (bf16_t*)(ws + 76800000);   //  76,800,000 B
    float*  al     = (float*)(ws + 153600000);   //   2,400,000 B
    float*  ar     = (float*)(ws + 156000000);   //   2,400,000 B
    int*    deg    = (int*)(ws + 158400000);     //     200,448 B
    int*    cursor = (int*)(ws + 158800896);     //     200,448 B
    int*    csrsrc = (int*)(ws + 159001344);     //   1,000,000 B
    bf16_t* wfb    = (bf16_t*)(ws + 160001344);  //       8,192 B
    bf16_t* wrb    = (bf16_t*)(ws + 160009536);  //       8,192 B
    bf16_t* ulb    = (bf16_t*)(ws + 160017728);  //       2,048 B
    bf16_t* urb    = (bf16_t*)(ws + 160019776);  //       2,048 B (end ~160 MB)

    (void)hipMemsetAsync(deg, 0, N_NODES * sizeof(int), stream);
    k_deg_prep<<<269, 256, 0, stream>>>(dst, deg, wfc, wres, attl, attr, wfb, wrb, ulb, urb);
    k_scan<<<1, 1024, 0, stream>>>(deg, cursor);
    k_fill_gemm<<<NGEMMB + NFILLB, 256, 0, stream>>>(src, dst, cursor, csrsrc,
                                                     h, wfb, wrb, ulb, urb, ft, resb, al, ar);
    k_agg<<<(N_NODES + 3) / 4, 256, 0, stream>>>(cursor, csrsrc, al, ar, ft, resb, out);
}

// Round 18
// 209.497 us; speedup vs baseline: 1.2680x; 1.2680x over previous
//
#include <hip/hip_runtime.h>
#include <hip/hip_bf16.h>

#define N_NODES 50000
#define N_EDGES 250000
#define NHEAD   12
#define NH      (N_NODES * NHEAD)   /* 600000 rows of 64 */
#define ROW_TILES (NH / 16)         /* 37500 */

typedef __bf16 bf16_t;
typedef __bf16 bf16x8 __attribute__((ext_vector_type(8)));
typedef __bf16 bf16x4 __attribute__((ext_vector_type(4)));
typedef float  f32x4  __attribute__((ext_vector_type(4)));

__device__ __forceinline__ bf16x8 cvt8(f32x4 a, f32x4 b) {
    bf16x8 r;
    r[0] = (bf16_t)a[0]; r[1] = (bf16_t)a[1]; r[2] = (bf16_t)a[2]; r[3] = (bf16_t)a[3];
    r[4] = (bf16_t)b[0]; r[5] = (bf16_t)b[1]; r[6] = (bf16_t)b[2]; r[7] = (bf16_t)b[3];
    return r;
}

// ---------------- prep: degree histogram (int4 edge reads), weight cvt, ul/ur ----------------
__global__ __launch_bounds__(256) void k_deg_prep(
    const int* __restrict__ dst, int* __restrict__ deg,
    const float* __restrict__ wfc, const float* __restrict__ wres,
    const float* __restrict__ attl, const float* __restrict__ attr,
    bf16_t* __restrict__ wfb, bf16_t* __restrict__ wrb,
    bf16_t* __restrict__ ulb, bf16_t* __restrict__ urb)
{
    int b = blockIdx.x;
    if (b < 245) {
        int i4 = b * 256 + threadIdx.x;          // 62500 int4s = 250000 edges exactly
        if (i4 < N_EDGES / 4) {
            int4 q = reinterpret_cast<const int4*>(dst)[i4];
            atomicAdd(&deg[q.x], 1);
            atomicAdd(&deg[q.y], 1);
            atomicAdd(&deg[q.z], 1);
            atomicAdd(&deg[q.w], 1);
        }
    } else if (b < 261) {
        int t = (b - 245) * 256 + threadIdx.x;   // 0..4095
        wfb[t] = (bf16_t)wfc[t];
        wrb[t] = (bf16_t)wres[t];
    } else if (b < 265) {
        int u = (b - 261) * 256 + threadIdx.x;   // 0..1023
        int hh = u >> 6, d = u & 63;
        float s = 0.f;
        if (hh < NHEAD) {
#pragma unroll 8
            for (int e = 0; e < 64; ++e) s += attl[hh * 64 + e] * wfc[e * 64 + d];
        }
        ulb[u] = (bf16_t)s;
    } else {
        int u = (b - 265) * 256 + threadIdx.x;   // 0..1023
        int hh = u >> 6, d = u & 63;
        float s = 0.f;
        if (hh < NHEAD) {
#pragma unroll 8
            for (int e = 0; e < 64; ++e) s += attr[hh * 64 + e] * wfc[e * 64 + d];
        }
        urb[u] = (bf16_t)s;
    }
}

// single block, 1024 threads, 52 nodes/thread. Writes ONLY cursor (=segment
// starts); fill atomics exhaust cursor into segment ENDs; k_agg reads
// beg=cursor[d-1], end=cursor[d].
__global__ __launch_bounds__(1024) void k_scan(const int* __restrict__ deg,
                                               int* __restrict__ cursor) {
    __shared__ int s[1024];
    const int CH = 52;
    int t = threadIdx.x;
    int base = t * CH;
    int loc[CH];
    if (base + CH <= N_NODES) {
        const int4* p = reinterpret_cast<const int4*>(deg + base);
#pragma unroll
        for (int i = 0; i < CH / 4; ++i) {
            int4 q = p[i];
            loc[4 * i + 0] = q.x; loc[4 * i + 1] = q.y;
            loc[4 * i + 2] = q.z; loc[4 * i + 3] = q.w;
        }
    } else {
#pragma unroll
        for (int i = 0; i < CH; ++i) {
            int idx = base + i;
            loc[i] = (idx < N_NODES) ? deg[idx] : 0;
        }
    }
    int sum = 0;
#pragma unroll
    for (int i = 0; i < CH; ++i) sum += loc[i];
    s[t] = sum;
    __syncthreads();
    for (int off = 1; off < 1024; off <<= 1) {
        int v = (t >= off) ? s[t - off] : 0;
        __syncthreads();
        s[t] += v;
        __syncthreads();
    }
    int run = s[t] - sum;
#pragma unroll
    for (int i = 0; i < CH; ++i) {
        int idx = base + i;
        if (idx < N_NODES) {
            cursor[idx] = run;
            run += loc[i];
        }
    }
}

// ---------------- fused persistent GEMM + CSR-fill ----------------
// Blocks 0..1874: persistent GEMM (starts immediately); blocks 1875..2851:
// CSR fill (latency-bound atomics, slots in around the GEMM).
// h loads are NONTEMPORAL (single-use, 153.6MB).
__global__ __launch_bounds__(256) void k_fill_gemm(
    const int* __restrict__ src, const int* __restrict__ dst,
    int* __restrict__ cursor, int* __restrict__ csr_src,
    const float* __restrict__ h,
    const bf16_t* __restrict__ wfb,
    const bf16_t* __restrict__ wrb,
    const bf16_t* __restrict__ ulb,
    const bf16_t* __restrict__ urb,
    bf16_t* __restrict__ ft,
    bf16_t* __restrict__ resb,
    float* __restrict__ al,
    float* __restrict__ ar)
{
    __shared__ bf16_t sb[4][2][16 * 72];
    if (blockIdx.x >= 1875) {
        int i = (blockIdx.x - 1875) * 256 + threadIdx.x;
        if (i < N_EDGES) {
            int d = dst[i];
            int pos = atomicAdd(&cursor[d], 1);
            csr_src[pos] = src[i];
        }
        return;
    }
    int bid  = blockIdx.x;
    int wv   = threadIdx.x >> 6;
    int lane = threadIdx.x & 63;
    int lr = lane & 15, lg = lane >> 4;
    int l8 = lane & 7,  lrow = lane >> 3;
    bf16_t* fs = &sb[wv][0][0];
    bf16_t* rs = &sb[wv][1][0];

    const f32x4*  hv  = reinterpret_cast<const f32x4*>(h);
    const bf16x8* wf  = reinterpret_cast<const bf16x8*>(wfb);
    const bf16x8* wr  = reinterpret_cast<const bf16x8*>(wrb);
    const bf16x8* ulv = reinterpret_cast<const bf16x8*>(ulb);
    const bf16x8* urv = reinterpret_cast<const bf16x8*>(urb);
    bf16x8 ul0 = ulv[lr * 8 + lg], ul1 = ulv[lr * 8 + 4 + lg];
    bf16x8 ur0 = urv[lr * 8 + lg], ur1 = urv[lr * 8 + 4 + lg];

    const int nw = 1875 * 4;                    // total gemm waves
    int tile = bid * 4 + wv;

    f32x4 c0, c1, c2, c3;
    if (tile < ROW_TILES) {
        int ab = (tile * 16 + lr) * 16 + lg * 2;
        c0 = __builtin_nontemporal_load(hv + ab);
        c1 = __builtin_nontemporal_load(hv + ab + 1);
        c2 = __builtin_nontemporal_load(hv + ab + 8);
        c3 = __builtin_nontemporal_load(hv + ab + 9);
    }
    while (tile < ROW_TILES) {
        int nxt = tile + nw;
        f32x4 n0, n1, n2, n3;
        if (nxt < ROW_TILES) {                  // prefetch next tile's A (NT)
            int ab = (nxt * 16 + lr) * 16 + lg * 2;
            n0 = __builtin_nontemporal_load(hv + ab);
            n1 = __builtin_nontemporal_load(hv + ab + 1);
            n2 = __builtin_nontemporal_load(hv + ab + 8);
            n3 = __builtin_nontemporal_load(hv + ab + 9);
        }
        bf16x8 a0 = cvt8(c0, c1), a1 = cvt8(c2, c3);
        int r0 = tile << 4;
        int r  = r0 + lr;
        int hh = r % NHEAD;

        // attn dots via MFMA: D[head][node]; static-index extraction only
        f32x4 dl = {0.f, 0.f, 0.f, 0.f}, dr = {0.f, 0.f, 0.f, 0.f};
        dl = __builtin_amdgcn_mfma_f32_16x16x32_bf16(ul0, a0, dl, 0, 0, 0);
        dl = __builtin_amdgcn_mfma_f32_16x16x32_bf16(ul1, a1, dl, 0, 0, 0);
        dr = __builtin_amdgcn_mfma_f32_16x16x32_bf16(ur0, a0, dr, 0, 0, 0);
        dr = __builtin_amdgcn_mfma_f32_16x16x32_bf16(ur1, a1, dr, 0, 0, 0);
        if (lg == (hh >> 2)) {
#pragma unroll
            for (int j = 0; j < 4; ++j)
                if ((hh & 3) == j) { al[r] = dl[j]; ar[r] = dr[j]; }
        }

        // main GEMMs -> LDS (padded stride 72)
#pragma unroll
        for (int nt = 0; nt < 4; ++nt) {
            int brow = (nt * 16 + lr) * 8;
            f32x4 z = {0.f, 0.f, 0.f, 0.f};
            z = __builtin_amdgcn_mfma_f32_16x16x32_bf16(wf[brow + lg],     a0, z, 0, 0, 0);
            z = __builtin_amdgcn_mfma_f32_16x16x32_bf16(wf[brow + 4 + lg], a1, z, 0, 0, 0);
            f32x4 y = {0.f, 0.f, 0.f, 0.f};
            y = __builtin_amdgcn_mfma_f32_16x16x32_bf16(wr[brow + lg],     a0, y, 0, 0, 0);
            y = __builtin_amdgcn_mfma_f32_16x16x32_bf16(wr[brow + 4 + lg], a1, y, 0, 0, 0);
            bf16x4 pf, pe;
#pragma unroll
            for (int j = 0; j < 4; ++j) { pf[j] = (bf16_t)z[j]; pe[j] = (bf16_t)y[j]; }
            *reinterpret_cast<bf16x4*>(fs + lr * 72 + nt * 16 + lg * 4) = pf;
            *reinterpret_cast<bf16x4*>(rs + lr * 72 + nt * 16 + lg * 4) = pe;
        }

        // LDS -> full-line stores: lane l8 owns 16 contiguous bytes of row lrow(+8k)
#pragma unroll
        for (int k = 0; k < 2; ++k) {
            int row = lrow + k * 8;
            bf16x8 vf = *reinterpret_cast<const bf16x8*>(fs + row * 72 + l8 * 8);
            bf16x8 vr = *reinterpret_cast<const bf16x8*>(rs + row * 72 + l8 * 8);
            *reinterpret_cast<bf16x8*>(ft   + (r0 + row) * 64 + l8 * 8) = vf;
            *reinterpret_cast<bf16x8*>(resb + (r0 + row) * 64 + l8 * 8) = vr;
        }

        c0 = n0; c1 = n1; c2 = n2; c3 = n3;
        tile = nxt;
    }
}

// ---------------- fused edge-softmax + aggregate + residual + relu ----------------
// ONE WAVE PER DST NODE, all 12 heads; DB=8 edges in flight (16 fat ft loads).
// Segments: beg = cur[d0-1] (post-fill), end = cur[d0]. Cooperative weights:
// lane l<48 computes (edge l/12 and l/12+4, head l%12) -> 2 gather instrs per
// 8-edge batch; shfl distributes. resb read nontemporal (single-use).
#define DB 8
__global__ __launch_bounds__(256) void k_agg(
    const int* __restrict__ cur, const int* __restrict__ csr_src,
    const float* __restrict__ al, const float* __restrict__ ar,
    const bf16_t* __restrict__ ft, const bf16_t* __restrict__ resb,
    float* __restrict__ out)
{
    int d0 = (blockIdx.x * 256 + threadIdx.x) >> 6;
    d0 = __builtin_amdgcn_readfirstlane(d0);
    if (d0 >= N_NODES) return;
    int l  = threadIdx.x & 63;
    int hA = l >> 3;              // part A: head l>>3, feats (l&7)*8..+7
    int hB = 8 + (l >> 4);        // part B: head 8+(l>>4), feats (l&15)*4..+3
    int u_l = l / 12;             // weight lanes: l<48 -> edge pair (u_l, u_l+4)
    int h_l = l - u_l * 12;
    int beg = d0 ? cur[d0 - 1] : 0;                       // s_load
    int end = cur[d0];
    float arW = 0.f;
    if (l < 48) arW = ar[d0 * NHEAD + h_l];

    float accA[8] = {0,0,0,0,0,0,0,0};
    float accB[4] = {0,0,0,0};
    float denA = 0.f, denB = 0.f;

    for (int j0 = beg; j0 < end; j0 += DB) {
        int idx[DB];
#pragma unroll
        for (int u = 0; u < DB; ++u) {
            int j = j0 + u;
            idx[u] = csr_src[(j < end) ? j : beg];        // scalar (uniform addr)
        }
        // cooperative weights: lanes 0..47, two edges each
        float wv0 = 0.f, wv1 = 0.f;
        {
            int e0 = idx[0], e1 = idx[4];
            e0 = (u_l == 1) ? idx[1] : e0;  e1 = (u_l == 1) ? idx[5] : e1;
            e0 = (u_l == 2) ? idx[2] : e0;  e1 = (u_l == 2) ? idx[6] : e1;
            e0 = (u_l == 3) ? idx[3] : e0;  e1 = (u_l == 3) ? idx[7] : e1;
            if (l < 48) {
                float x0 = al[e0 * NHEAD + h_l] + arW;
                float x1 = al[e1 * NHEAD + h_l] + arW;
                x0 = (x0 > 0.f) ? x0 : 0.2f * x0;         // leaky_relu
                x1 = (x1 > 0.f) ? x1 : 0.2f * x1;
                wv0 = ((j0 + u_l)     < end) ? __expf(x0) : 0.f;
                wv1 = ((j0 + 4 + u_l) < end) ? __expf(x1) : 0.f;
            }
        }
        float wA[DB], wB[DB];
#pragma unroll
        for (int u = 0; u < 4; ++u) {
            wA[u]     = __shfl(wv0, u * 12 + hA, 64);
            wB[u]     = __shfl(wv0, u * 12 + hB, 64);
            wA[u + 4] = __shfl(wv1, u * 12 + hA, 64);
            wB[u + 4] = __shfl(wv1, u * 12 + hB, 64);
        }
        bf16x8 vA[DB]; bf16x4 vB[DB];
#pragma unroll
        for (int u = 0; u < DB; ++u) {
            const bf16_t* row = ft + idx[u] * 768;
            vA[u] = *reinterpret_cast<const bf16x8*>(row + 8 * l);
            vB[u] = *reinterpret_cast<const bf16x4*>(row + 512 + 4 * l);
        }
#pragma unroll
        for (int u = 0; u < DB; ++u) {
            denA += wA[u]; denB += wB[u];
#pragma unroll
            for (int k = 0; k < 8; ++k) accA[k] += wA[u] * (float)vA[u][k];
#pragma unroll
            for (int k = 0; k < 4; ++k) accB[k] += wB[u] * (float)vB[u][k];
        }
    }

    const bf16_t* rrow = resb + d0 * 768;
    bf16x8 rA = __builtin_nontemporal_load(reinterpret_cast<const bf16x8*>(rrow + 8 * l));
    bf16x4 rB = __builtin_nontemporal_load(reinterpret_cast<const bf16x4*>(rrow + 512 + 4 * l));
    float* orow = out + d0 * 768;
    f32x4 o0, o1, o2;
    float ia = 1.f / denA, ib = 1.f / denB;
#pragma unroll
    for (int k = 0; k < 4; ++k) {
        float x = (float)rA[k] + accA[k] * ia;         o0[k] = x > 0.f ? x : 0.f;
        float y = (float)rA[k + 4] + accA[k + 4] * ia; o1[k] = y > 0.f ? y : 0.f;
        float z = (float)rB[k] + accB[k] * ib;         o2[k] = z > 0.f ? z : 0.f;
    }
    __builtin_nontemporal_store(o0, reinterpret_cast<f32x4*>(orow + 8 * l));
    __builtin_nontemporal_store(o1, reinterpret_cast<f32x4*>(orow + 8 * l + 4));
    __builtin_nontemporal_store(o2, reinterpret_cast<f32x4*>(orow + 512 + 4 * l));
}

extern "C" void kernel_launch(void* const* d_in, const int* in_sizes, int n_in,
                              void* d_out, int out_size, void* d_ws, size_t ws_size,
                              hipStream_t stream) {
    const float* h    = (const float*)d_in[0];
    const float* wfc  = (const float*)d_in[1];
    const float* attl = (const float*)d_in[2];
    const float* attr = (const float*)d_in[3];
    const float* wres = (const float*)d_in[4];
    const int*   src  = (const int*)d_in[5];
    const int*   dst  = (const int*)d_in[6];
    float* out = (float*)d_out;

    char* ws = (char*)d_ws;
    bf16_t* ft     = (bf16_t*)(ws + 0);          //  76,800,000 B
    bf16_t* resb   = (bf16_t*)(ws + 76800000);   //  76,800,000 B
    float*  al     = (float*)(ws + 153600000);   //   2,400,000 B
    float*  ar     = (float*)(ws + 156000000);   //   2,400,000 B
    int*    deg    = (int*)(ws + 158400000);     //     200,448 B
    int*    cursor = (int*)(ws + 158800896);     //     200,448 B
    int*    csrsrc = (int*)(ws + 159001344);     //   1,000,000 B
    bf16_t* wfb    = (bf16_t*)(ws + 160001344);  //       8,192 B
    bf16_t* wrb    = (bf16_t*)(ws + 160009536);  //       8,192 B
    bf16_t* ulb    = (bf16_t*)(ws + 160017728);  //       2,048 B
    bf16_t* urb    = (bf16_t*)(ws + 160019776);  //       2,048 B (end ~160 MB)

    (void)hipMemsetAsync(deg, 0, N_NODES * sizeof(int), stream);
    k_deg_prep<<<269, 256, 0, stream>>>(dst, deg, wfc, wres, attl, attr, wfb, wrb, ulb, urb);
    k_scan<<<1, 1024, 0, stream>>>(deg, cursor);
    k_fill_gemm<<<1875 + 977, 256, 0, stream>>>(src, dst, cursor, csrsrc,
                                                h, wfb, wrb, ulb, urb, ft, resb, al, ar);
    k_agg<<<(N_NODES + 3) / 4, 256, 0, stream>>>(cursor, csrsrc, al, ar, ft, resb, out);
}